// Round 1
// baseline (694.323 us; speedup 1.0000x reference)
//
#include <hip/hip_runtime.h>
#include <math.h>

// Problem constants (match reference)
#define B_ 4
#define N_ 500
#define C_ 80
#define T_ 28
#define TT 784       // T*T
#define M_ 16
#define H_ 800
#define W_ 800
#define CAND_K 10
#define EPS 1e-8f

// ---- workspace layout (in floats) ----
#define OFF_GM    0                          // [B][M][TT] binarized cropped gt masks
#define OFF_GSUM  (OFF_GM + B_*M_*TT)        // [B][M]
#define OFF_COST  (OFF_GSUM + B_*M_)         // [B][N][M]
#define OFF_IOUS  (OFF_COST + B_*N_*M_)      // [B][N][M]
#define OFF_MATCH (OFF_IOUS + B_*N_*M_)      // [B][N][M]
#define OFF_VALID (OFF_MATCH + B_*N_*M_)     // [B][N]
#define OFF_ACC   (OFF_VALID + B_*N_)        // [5] cls,l1,giou,mask,num_fg
#define WS_FLOATS (OFF_ACC + 8)

// ------------------------------------------------------------------
// K1: ROIAlign-style bilinear crop of gt mask to 28x28, binarize >=0.5
// one block per (b,m)
__global__ __launch_bounds__(256) void crop_kernel(
    const float* __restrict__ gtm, const float* __restrict__ gboxes,
    float* __restrict__ gm, float* __restrict__ gsum) {
  int bm = blockIdx.x;
  const float* img = gtm + (size_t)bm * (H_ * W_);
  float x1 = gboxes[bm*4+0], y1 = gboxes[bm*4+1];
  float x2 = gboxes[bm*4+2], y2 = gboxes[bm*4+3];
  float part = 0.f;
  for (int t = threadIdx.x; t < TT; t += blockDim.x) {
    int i = t / T_, j = t - i * T_;
    float y = y1 + (i + 0.5f) * (y2 - y1) / T_ - 0.5f;
    float x = x1 + (j + 0.5f) * (x2 - x1) / T_ - 0.5f;
    int y0 = (int)floorf(y), x0 = (int)floorf(x);
    float fy = y - (float)y0, fx = x - (float)x0;
    float v = 0.f;
#pragma unroll
    for (int dy = 0; dy < 2; ++dy)
#pragma unroll
      for (int dx = 0; dx < 2; ++dx) {
        int yy = y0 + dy, xx = x0 + dx;
        float w = (dy ? fy : 1.f - fy) * (dx ? fx : 1.f - fx);
        if (yy >= 0 && yy < H_ && xx >= 0 && xx < W_)
          v += w * img[yy * W_ + xx];
      }
    float g = (v >= 0.5f) ? 1.f : 0.f;
    gm[(size_t)bm * TT + t] = g;
    part += g;
  }
  __shared__ float sb[4];
  for (int off = 32; off; off >>= 1) part += __shfl_down(part, off, 64);
  int lane = threadIdx.x & 63, w = threadIdx.x >> 6;
  if (lane == 0) sb[w] = part;
  __syncthreads();
  if (threadIdx.x == 0) gsum[bm] = sb[0] + sb[1] + sb[2] + sb[3];
}

// ------------------------------------------------------------------
// K2: full cost matrix + raw ious + valid flags. One block per (b,n).
// Only touches pred_masks at classes gt_cls[m] (80x less traffic than the
// reference's full einsum).
__global__ __launch_bounds__(256) void cost_kernel(
    const float* __restrict__ logits, const float* __restrict__ boxes,
    const float* __restrict__ masks, const int* __restrict__ gcls,
    const float* __restrict__ gboxes, const float* __restrict__ imgsz,
    const float* __restrict__ gm, const float* __restrict__ gsum,
    float* __restrict__ cost, float* __restrict__ ious,
    float* __restrict__ validf) {
  int blk = blockIdx.x;
  int b = blk / N_, n = blk - b * N_;
  int tid = threadIdx.x;
  __shared__ float s_ssum[M_], s_inter[M_];
  __shared__ float2 wbuf[4];
  const size_t nb_off = (size_t)(b * N_ + n);

  // 16 cooperative reductions: sum_t sigmoid(mask), sum_t sigmoid(mask)*gm
  for (int m = 0; m < M_; ++m) {
    int gc = gcls[b * M_ + m];
    const float4* mp = (const float4*)(masks + (nb_off * C_ + gc) * TT);
    const float4* gp = (const float4*)(gm + (size_t)(b * M_ + m) * TT);
    float si = 0.f, sg = 0.f;
    if (tid < TT / 4) {
      float4 mv = mp[tid];
      float4 gv = gp[tid];
      float p0 = 1.f / (1.f + expf(-mv.x));
      float p1 = 1.f / (1.f + expf(-mv.y));
      float p2 = 1.f / (1.f + expf(-mv.z));
      float p3 = 1.f / (1.f + expf(-mv.w));
      si = p0 + p1 + p2 + p3;
      sg = p0 * gv.x + p1 * gv.y + p2 * gv.z + p3 * gv.w;
    }
    for (int off = 32; off; off >>= 1) {
      si += __shfl_down(si, off, 64);
      sg += __shfl_down(sg, off, 64);
    }
    int lane = tid & 63, w = tid >> 6;
    if (lane == 0) wbuf[w] = make_float2(si, sg);
    __syncthreads();
    if (tid == 0) {
      s_ssum[m]  = wbuf[0].x + wbuf[1].x + wbuf[2].x + wbuf[3].x;
      s_inter[m] = wbuf[0].y + wbuf[1].y + wbuf[2].y + wbuf[3].y;
    }
    __syncthreads();
  }

  // per-(n,m) scalar cost on threads 0..15 (all in wave 0)
  float bx1 = boxes[nb_off*4+0], by1 = boxes[nb_off*4+1];
  float bx2 = boxes[nb_off*4+2], by2 = boxes[nb_off*4+3];
  float cx = (bx1 + bx2) * 0.5f, cy = (by1 + by2) * 0.5f;
  bool flag = false, in_box = false, in_ctr = false;
  float gx1 = 0, gy1 = 0, gx2 = 0, gy2 = 0;
  if (tid < M_) {
    int gi = (b * M_ + tid) * 4;
    gx1 = gboxes[gi+0]; gy1 = gboxes[gi+1]; gx2 = gboxes[gi+2]; gy2 = gboxes[gi+3];
    in_box = (cx > gx1) && (cx < gx2) && (cy > gy1) && (cy < gy2);
    float gcx = (gx1 + gx2) * 0.5f, gcy = (gy1 + gy2) * 0.5f;
    float gw = gx2 - gx1, gh = gy2 - gy1;
    in_ctr = (fabsf(cx - gcx) < 0.25f * gw) && (fabsf(cy - gcy) < 0.25f * gh);
    flag = in_box || in_ctr;
  }
  unsigned long long bal = __ballot(flag);   // wave-0 ballot over m=0..15
  bool valid = (bal != 0ULL);
  if (tid == 0) validf[nb_off] = valid ? 1.f : 0.f;

  if (tid < M_) {
    int m = tid;
    int gc = gcls[b * M_ + m];
    // focal matching cost at class gc
    float lg = logits[nb_off * C_ + gc];
    float p = 1.f / (1.f + expf(-lg));
    float pos = -logf(p + EPS) * 0.25f * (1.f - p) * (1.f - p);
    float neg = -logf(1.f - p + EPS) * 0.75f * p * p;
    float ccost = 2.f * (pos - neg);
    // normalized boxes
    float s0 = imgsz[b*4+0], s1 = imgsz[b*4+1], s2 = imgsz[b*4+2], s3 = imgsz[b*4+3];
    float nbx1 = bx1/s0, nby1 = by1/s1, nbx2 = bx2/s2, nby2 = by2/s3;
    float ngx1 = gx1/s0, ngy1 = gy1/s1, ngx2 = gx2/s2, ngy2 = gy2/s3;
    float l1 = 5.f * (fabsf(nbx1-ngx1) + fabsf(nby1-ngy1) +
                      fabsf(nbx2-ngx2) + fabsf(nby2-ngy2));
    // giou on normalized boxes
    float ilx = fmaxf(nbx1, ngx1), ily = fmaxf(nby1, ngy1);
    float irx = fminf(nbx2, ngx2), iry = fminf(nby2, ngy2);
    float iw = fmaxf(irx - ilx, 0.f), ih = fmaxf(iry - ily, 0.f);
    float inter = iw * ih;
    float a1 = (nbx2 - nbx1) * (nby2 - nby1);
    float a2 = (ngx2 - ngx1) * (ngy2 - ngy1);
    float uni = a1 + a2 - inter;
    float iou = inter / (uni + EPS);
    float elx = fminf(nbx1, ngx1), ely = fminf(nby1, ngy1);
    float erx = fmaxf(nbx2, ngx2), ery = fmaxf(nby2, ngy2);
    float ew = fmaxf(erx - elx, 0.f), eh = fmaxf(ery - ely, 0.f);
    float enc = ew * eh;
    float giou = iou - (enc - uni) / (enc + EPS);
    float gcost = 2.f * (1.f - giou);
    // dice cost
    float mcost = 5.f * (1.f - 2.f * s_inter[m] / (s_ssum[m] + gsum[b*M_+m] + EPS));
    float c = ccost + l1 + gcost + mcost;
    if (!(in_box && in_ctr)) c += 1e5f;
    if (!valid) c += 1e9f;
    cost[nb_off * M_ + m] = c;
    // raw-pixel iou for dynamic-k
    float rlx = fmaxf(bx1, gx1), rly = fmaxf(by1, gy1);
    float rrx = fminf(bx2, gx2), rry = fminf(by2, gy2);
    float rw = fmaxf(rrx - rlx, 0.f), rh = fmaxf(rry - rly, 0.f);
    float rinter = rw * rh;
    float ra1 = (bx2 - bx1) * (by2 - by1);
    float ra2 = (gx2 - gx1) * (gy2 - gy1);
    float runi = ra1 + ra2 - rinter;
    float riou = rinter / (runi + EPS);
    ious[nb_off * M_ + m] = valid ? riou : 0.f;
  }
}

// ------------------------------------------------------------------
// K3: SimOTA column matching. One block per (b,m).
// top-10 ious (sorted desc, sum -> dyn_k), then top-10 min-cost indices
// with lower-index tie-break (jax.lax.top_k semantics).
__global__ __launch_bounds__(256) void match_kernel(
    const float* __restrict__ cost, const float* __restrict__ ious,
    float* __restrict__ matching) {
  int b = blockIdx.x / M_, m = blockIdx.x - b * M_;
  int tid = threadIdx.x;
  __shared__ float cc[N_], io[N_];
  __shared__ float swv[4];
  __shared__ int swi[4];
  __shared__ int s_dk;
  for (int n = tid; n < N_; n += 256) {
    cc[n] = cost[(size_t)(b * N_ + n) * M_ + m];
    io[n] = ious[(size_t)(b * N_ + n) * M_ + m];
  }
  __syncthreads();
  int lane = tid & 63, w = tid >> 6;
  float s = 0.f;  // meaningful on tid 0 only
  for (int k = 0; k < CAND_K; ++k) {
    float bv = -1e30f; int bi = 0x7fffffff;
    for (int n = tid; n < N_; n += 256) {
      float v = io[n];
      if (v > bv || (v == bv && n < bi)) { bv = v; bi = n; }
    }
    for (int off = 32; off; off >>= 1) {
      float ov = __shfl_down(bv, off, 64);
      int oi = __shfl_down(bi, off, 64);
      if (ov > bv || (ov == bv && oi < bi)) { bv = ov; bi = oi; }
    }
    if (lane == 0) { swv[w] = bv; swi[w] = bi; }
    __syncthreads();
    if (tid == 0) {
      float Bv = swv[0]; int Bi = swi[0];
      for (int ww = 1; ww < 4; ++ww)
        if (swv[ww] > Bv || (swv[ww] == Bv && swi[ww] < Bi)) { Bv = swv[ww]; Bi = swi[ww]; }
      s += Bv;          // descending order, matches top_k().sum()
      io[Bi] = -1e30f;
    }
    __syncthreads();
  }
  if (tid == 0) {
    int dk = (int)s;              // astype(int32) truncation
    if (dk < 1) dk = 1;           // clip(..., 1, None)
    s_dk = dk;
  }
  __syncthreads();
  int dk = s_dk;
  for (int k = 0; k < CAND_K; ++k) {
    float bv = 1e30f; int bi = 0x7fffffff;
    for (int n = tid; n < N_; n += 256) {
      float v = cc[n];
      if (v < bv || (v == bv && n < bi)) { bv = v; bi = n; }
    }
    for (int off = 32; off; off >>= 1) {
      float ov = __shfl_down(bv, off, 64);
      int oi = __shfl_down(bi, off, 64);
      if (ov < bv || (ov == bv && oi < bi)) { bv = ov; bi = oi; }
    }
    if (lane == 0) { swv[w] = bv; swi[w] = bi; }
    __syncthreads();
    if (tid == 0) {
      float Bv = swv[0]; int Bi = swi[0];
      for (int ww = 1; ww < 4; ++ww)
        if (swv[ww] < Bv || (swv[ww] == Bv && swi[ww] < Bi)) { Bv = swv[ww]; Bi = swi[ww]; }
      if (k < dk) matching[(size_t)(b * N_ + Bi) * M_ + m] = 1.f;
      cc[Bi] = 1e30f;
    }
    __syncthreads();
  }
}

// ------------------------------------------------------------------
// K4: per-prediction losses. One wave (64 lanes) per (b,n).
__global__ __launch_bounds__(256) void loss_kernel(
    const float* __restrict__ logits, const float* __restrict__ boxes,
    const float* __restrict__ masks, const int* __restrict__ gcls,
    const float* __restrict__ gboxes, const float* __restrict__ imgsz,
    const float* __restrict__ gm, const float* __restrict__ gsum,
    const float* __restrict__ matching, const float* __restrict__ cost,
    const float* __restrict__ validf, float* __restrict__ acc) {
  int gid = blockIdx.x * blockDim.x + threadIdx.x;
  int wid = gid >> 6;
  int lane = threadIdx.x & 63;
  if (wid >= B_ * N_) return;
  int b = wid / N_, n = wid - b * N_;
  size_t nb_off = (size_t)(b * N_ + n);

  int matched = 0, fg = 0;
  if (lane == 0) {
    const float* mrow = matching + nb_off * M_;
    const float* crow = cost + nb_off * M_;
    float msum = 0.f; int first = -1;
    for (int m = 0; m < M_; ++m) {
      float v = mrow[m];
      msum += v;
      if (first < 0 && v > 0.5f) first = m;
    }
    float fgs;
    if (msum > 1.f) {                 // multi: replace with one_hot(argmin cost)
      float bv = crow[0]; int bi = 0;
      for (int m = 1; m < M_; ++m) if (crow[m] < bv) { bv = crow[m]; bi = m; }
      matched = bi; fgs = 1.f;
    } else {
      matched = (first >= 0) ? first : 0;   // argmax of 0/1 row, first occurrence
      fgs = msum;
    }
    fg = (fgs > 0.f && validf[nb_off] > 0.5f) ? 1 : 0;
  }
  matched = __shfl(matched, 0, 64);
  fg = __shfl(fg, 0, 64);
  if (!fg) return;

  int tcls = gcls[b * M_ + matched];
  // focal loss over all C classes
  float fsum = 0.f;
  for (int c = lane; c < C_; c += 64) {
    float l = logits[nb_off * C_ + c];
    float p = 1.f / (1.f + expf(-l));
    float tgt = (c == tcls) ? 1.f : 0.f;
    float ce = fmaxf(l, 0.f) - l * tgt + log1pf(expf(-fabsf(l)));
    float pt = p * tgt + (1.f - p) * (1.f - tgt);
    float om = 1.f - pt;
    float wf = 0.25f * tgt + 0.75f * (1.f - tgt);
    fsum += ce * om * om * wf;
  }
  // dice loss vs matched gt mask
  float mi = 0.f, ps = 0.f;
  const float* pmrow = masks + (nb_off * C_ + tcls) * TT;
  const float* gmrow = gm + (size_t)(b * M_ + matched) * TT;
  for (int t = lane; t < TT; t += 64) {
    float pm = 1.f / (1.f + expf(-pmrow[t]));
    mi += pm * gmrow[t];
    ps += pm;
  }
  for (int off = 32; off; off >>= 1) {
    fsum += __shfl_down(fsum, off, 64);
    mi   += __shfl_down(mi, off, 64);
    ps   += __shfl_down(ps, off, 64);
  }
  if (lane == 0) {
    float bx1 = boxes[nb_off*4+0], by1 = boxes[nb_off*4+1];
    float bx2 = boxes[nb_off*4+2], by2 = boxes[nb_off*4+3];
    int gi = (b * M_ + matched) * 4;
    float gx1 = gboxes[gi+0], gy1 = gboxes[gi+1], gx2 = gboxes[gi+2], gy2 = gboxes[gi+3];
    float s0 = imgsz[b*4+0], s1 = imgsz[b*4+1], s2 = imgsz[b*4+2], s3 = imgsz[b*4+3];
    float nbx1 = bx1/s0, nby1 = by1/s1, nbx2 = bx2/s2, nby2 = by2/s3;
    float ngx1 = gx1/s0, ngy1 = gy1/s1, ngx2 = gx2/s2, ngy2 = gy2/s3;
    float l1 = fabsf(nbx1-ngx1) + fabsf(nby1-ngy1) + fabsf(nbx2-ngx2) + fabsf(nby2-ngy2);
    float ilx = fmaxf(nbx1, ngx1), ily = fmaxf(nby1, ngy1);
    float irx = fminf(nbx2, ngx2), iry = fminf(nby2, ngy2);
    float iw = fmaxf(irx - ilx, 0.f), ih = fmaxf(iry - ily, 0.f);
    float inter = iw * ih;
    float a1 = (nbx2 - nbx1) * (nby2 - nby1);
    float a2 = (ngx2 - ngx1) * (ngy2 - ngy1);
    float uni = a1 + a2 - inter;
    float iou = inter / (uni + EPS);
    float elx = fminf(nbx1, ngx1), ely = fminf(nby1, ngy1);
    float erx = fmaxf(nbx2, ngx2), ery = fmaxf(nby2, ngy2);
    float ew = fmaxf(erx - elx, 0.f), eh = fmaxf(ery - ely, 0.f);
    float enc = ew * eh;
    float giou = iou - (enc - uni) / (enc + EPS);
    float gterm = 1.f - giou;
    float mu = ps + gsum[b * M_ + matched] + EPS;
    float mterm = 1.f - 2.f * mi / mu;
    atomicAdd(&acc[0], fsum);
    atomicAdd(&acc[1], l1);
    atomicAdd(&acc[2], gterm);
    atomicAdd(&acc[3], mterm);
    atomicAdd(&acc[4], 1.f);
  }
}

// ------------------------------------------------------------------
__global__ void finalize_kernel(const float* __restrict__ acc, float* __restrict__ out) {
  if (threadIdx.x == 0 && blockIdx.x == 0) {
    float nf = acc[4];
    out[0] = 2.f * acc[0] / nf;   // CLS_W
    out[1] = 5.f * acc[1] / nf;   // L1_W
    out[2] = 2.f * acc[2] / nf;   // GIOU_W
    out[3] = 5.f * acc[3] / nf;   // MASK_W
  }
}

// ------------------------------------------------------------------
extern "C" void kernel_launch(void* const* d_in, const int* in_sizes, int n_in,
                              void* d_out, int out_size, void* d_ws, size_t ws_size,
                              hipStream_t stream) {
  const float* logits = (const float*)d_in[0];
  const float* boxes  = (const float*)d_in[1];
  const float* masks  = (const float*)d_in[2];
  const int*   gcls   = (const int*)d_in[3];
  const float* gboxes = (const float*)d_in[4];
  const float* gtm    = (const float*)d_in[5];
  const float* imgsz  = (const float*)d_in[6];

  float* ws       = (float*)d_ws;
  float* gm       = ws + OFF_GM;
  float* gsum     = ws + OFF_GSUM;
  float* cost     = ws + OFF_COST;
  float* ious     = ws + OFF_IOUS;
  float* matching = ws + OFF_MATCH;
  float* validf   = ws + OFF_VALID;
  float* acc      = ws + OFF_ACC;

  // ws is poisoned 0xAA before every launch — zero what we accumulate into
  hipMemsetAsync(matching, 0, (size_t)B_ * N_ * M_ * sizeof(float), stream);
  hipMemsetAsync(acc, 0, 8 * sizeof(float), stream);

  crop_kernel<<<B_ * M_, 256, 0, stream>>>(gtm, gboxes, gm, gsum);
  cost_kernel<<<B_ * N_, 256, 0, stream>>>(logits, boxes, masks, gcls, gboxes,
                                           imgsz, gm, gsum, cost, ious, validf);
  match_kernel<<<B_ * M_, 256, 0, stream>>>(cost, ious, matching);
  loss_kernel<<<(B_ * N_ * 64 + 255) / 256, 256, 0, stream>>>(
      logits, boxes, masks, gcls, gboxes, imgsz, gm, gsum, matching, cost,
      validf, acc);
  finalize_kernel<<<1, 64, 0, stream>>>(acc, (float*)d_out);
}

// Round 2
// 685.094 us; speedup vs baseline: 1.0135x; 1.0135x over previous
//
#include <hip/hip_runtime.h>
#include <math.h>

// Problem constants (match reference)
#define B_ 4
#define N_ 500
#define C_ 80
#define T_ 28
#define TT 784       // T*T
#define M_ 16
#define H_ 800
#define W_ 800
#define CAND_K 10
#define EPS 1e-8f

// ---- workspace layout (in floats) ----
#define OFF_GM    0                          // [B][M][TT] binarized cropped gt masks
#define OFF_GSUM  (OFF_GM + B_*M_*TT)        // [B][M]
#define OFF_COST  (OFF_GSUM + B_*M_)         // [B][N][M]
#define OFF_IOUS  (OFF_COST + B_*N_*M_)      // [B][N][M]
#define OFF_MATCH (OFF_IOUS + B_*N_*M_)      // [B][N][M]
#define OFF_VALID (OFF_MATCH + B_*N_*M_)     // [B][N]
#define OFF_ACC   (OFF_VALID + B_*N_)        // [5] cls,l1,giou,mask,num_fg
#define WS_FLOATS (OFF_ACC + 8)

// ------------------------------------------------------------------
// K1: ROIAlign-style bilinear crop of gt mask to 28x28, binarize >=0.5
// one block per (b,m). Block 0 also zero-inits the loss accumulators
// (replaces a hipMemsetAsync graph node; loss_kernel runs 3 nodes later).
__global__ __launch_bounds__(256) void crop_kernel(
    const float* __restrict__ gtm, const float* __restrict__ gboxes,
    float* __restrict__ gm, float* __restrict__ gsum, float* __restrict__ acc) {
  if (blockIdx.x == 0 && threadIdx.x < 8) acc[threadIdx.x] = 0.f;
  int bm = blockIdx.x;
  const float* img = gtm + (size_t)bm * (H_ * W_);
  float x1 = gboxes[bm*4+0], y1 = gboxes[bm*4+1];
  float x2 = gboxes[bm*4+2], y2 = gboxes[bm*4+3];
  float part = 0.f;
  for (int t = threadIdx.x; t < TT; t += blockDim.x) {
    int i = t / T_, j = t - i * T_;
    float y = y1 + (i + 0.5f) * (y2 - y1) / T_ - 0.5f;
    float x = x1 + (j + 0.5f) * (x2 - x1) / T_ - 0.5f;
    int y0 = (int)floorf(y), x0 = (int)floorf(x);
    float fy = y - (float)y0, fx = x - (float)x0;
    float v = 0.f;
#pragma unroll
    for (int dy = 0; dy < 2; ++dy)
#pragma unroll
      for (int dx = 0; dx < 2; ++dx) {
        int yy = y0 + dy, xx = x0 + dx;
        float w = (dy ? fy : 1.f - fy) * (dx ? fx : 1.f - fx);
        if (yy >= 0 && yy < H_ && xx >= 0 && xx < W_)
          v += w * img[yy * W_ + xx];
      }
    float g = (v >= 0.5f) ? 1.f : 0.f;
    gm[(size_t)bm * TT + t] = g;
    part += g;
  }
  __shared__ float sb[4];
  for (int off = 32; off; off >>= 1) part += __shfl_down(part, off, 64);
  int lane = threadIdx.x & 63, w = threadIdx.x >> 6;
  if (lane == 0) sb[w] = part;
  __syncthreads();
  if (threadIdx.x == 0) gsum[bm] = sb[0] + sb[1] + sb[2] + sb[3];
}

// ------------------------------------------------------------------
// K2: full cost matrix + raw ious + valid flags. One block per (b,n).
// Wave w owns m = {w, w+4, w+8, w+12}: wave-level shfl reductions only,
// NO __syncthreads() in the m-loop (R0 had 32 barriers/block, each draining
// vmcnt(0) on an HBM-latency load — the classic barrier-drain stall).
__global__ __launch_bounds__(256) void cost_kernel(
    const float* __restrict__ logits, const float* __restrict__ boxes,
    const float* __restrict__ masks, const int* __restrict__ gcls,
    const float* __restrict__ gboxes, const float* __restrict__ imgsz,
    const float* __restrict__ gm, const float* __restrict__ gsum,
    float* __restrict__ cost, float* __restrict__ ious,
    float* __restrict__ validf) {
  int blk = blockIdx.x;
  int b = blk / N_, n = blk - b * N_;
  int tid = threadIdx.x;
  int lane = tid & 63, wave = tid >> 6;
  __shared__ float s_ssum[M_], s_inter[M_];
  const size_t nb_off = (size_t)(b * N_ + n);

  // 16 cooperative reductions: sum_t sigmoid(mask), sum_t sigmoid(mask)*gm
  for (int m = wave; m < M_; m += 4) {
    int gc = gcls[b * M_ + m];
    const float4* mp = (const float4*)(masks + (nb_off * C_ + gc) * TT);
    const float4* gp = (const float4*)(gm + (size_t)(b * M_ + m) * TT);
    float si = 0.f, sg = 0.f;
    for (int t = lane; t < TT / 4; t += 64) {
      float4 mv = mp[t];
      float4 gv = gp[t];
      float p0 = 1.f / (1.f + expf(-mv.x));
      float p1 = 1.f / (1.f + expf(-mv.y));
      float p2 = 1.f / (1.f + expf(-mv.z));
      float p3 = 1.f / (1.f + expf(-mv.w));
      si += p0 + p1 + p2 + p3;
      sg += p0 * gv.x + p1 * gv.y + p2 * gv.z + p3 * gv.w;
    }
    for (int off = 32; off; off >>= 1) {
      si += __shfl_down(si, off, 64);
      sg += __shfl_down(sg, off, 64);
    }
    if (lane == 0) { s_ssum[m] = si; s_inter[m] = sg; }
  }
  __syncthreads();   // the ONLY block barrier

  // per-(n,m) scalar cost on threads 0..15 (all in wave 0)
  float bx1 = boxes[nb_off*4+0], by1 = boxes[nb_off*4+1];
  float bx2 = boxes[nb_off*4+2], by2 = boxes[nb_off*4+3];
  float cx = (bx1 + bx2) * 0.5f, cy = (by1 + by2) * 0.5f;
  bool flag = false, in_box = false, in_ctr = false;
  float gx1 = 0, gy1 = 0, gx2 = 0, gy2 = 0;
  if (tid < M_) {
    int gi = (b * M_ + tid) * 4;
    gx1 = gboxes[gi+0]; gy1 = gboxes[gi+1]; gx2 = gboxes[gi+2]; gy2 = gboxes[gi+3];
    in_box = (cx > gx1) && (cx < gx2) && (cy > gy1) && (cy < gy2);
    float gcx = (gx1 + gx2) * 0.5f, gcy = (gy1 + gy2) * 0.5f;
    float gw = gx2 - gx1, gh = gy2 - gy1;
    in_ctr = (fabsf(cx - gcx) < 0.25f * gw) && (fabsf(cy - gcy) < 0.25f * gh);
    flag = in_box || in_ctr;
  }
  unsigned long long bal = __ballot(flag);   // wave-0 ballot over m=0..15
  bool valid = (bal != 0ULL);
  if (tid == 0) validf[nb_off] = valid ? 1.f : 0.f;

  if (tid < M_) {
    int m = tid;
    int gc = gcls[b * M_ + m];
    // focal matching cost at class gc
    float lg = logits[nb_off * C_ + gc];
    float p = 1.f / (1.f + expf(-lg));
    float pos = -logf(p + EPS) * 0.25f * (1.f - p) * (1.f - p);
    float neg = -logf(1.f - p + EPS) * 0.75f * p * p;
    float ccost = 2.f * (pos - neg);
    // normalized boxes
    float s0 = imgsz[b*4+0], s1 = imgsz[b*4+1], s2 = imgsz[b*4+2], s3 = imgsz[b*4+3];
    float nbx1 = bx1/s0, nby1 = by1/s1, nbx2 = bx2/s2, nby2 = by2/s3;
    float ngx1 = gx1/s0, ngy1 = gy1/s1, ngx2 = gx2/s2, ngy2 = gy2/s3;
    float l1 = 5.f * (fabsf(nbx1-ngx1) + fabsf(nby1-ngy1) +
                      fabsf(nbx2-ngx2) + fabsf(nby2-ngy2));
    // giou on normalized boxes
    float ilx = fmaxf(nbx1, ngx1), ily = fmaxf(nby1, ngy1);
    float irx = fminf(nbx2, ngx2), iry = fminf(nby2, ngy2);
    float iw = fmaxf(irx - ilx, 0.f), ih = fmaxf(iry - ily, 0.f);
    float inter = iw * ih;
    float a1 = (nbx2 - nbx1) * (nby2 - nby1);
    float a2 = (ngx2 - ngx1) * (ngy2 - ngy1);
    float uni = a1 + a2 - inter;
    float iou = inter / (uni + EPS);
    float elx = fminf(nbx1, ngx1), ely = fminf(nby1, ngy1);
    float erx = fmaxf(nbx2, ngx2), ery = fmaxf(nby2, ngy2);
    float ew = fmaxf(erx - elx, 0.f), eh = fmaxf(ery - ely, 0.f);
    float enc = ew * eh;
    float giou = iou - (enc - uni) / (enc + EPS);
    float gcost = 2.f * (1.f - giou);
    // dice cost
    float mcost = 5.f * (1.f - 2.f * s_inter[m] / (s_ssum[m] + gsum[b*M_+m] + EPS));
    float c = ccost + l1 + gcost + mcost;
    if (!(in_box && in_ctr)) c += 1e5f;
    if (!valid) c += 1e9f;
    cost[nb_off * M_ + m] = c;
    // raw-pixel iou for dynamic-k
    float rlx = fmaxf(bx1, gx1), rly = fmaxf(by1, gy1);
    float rrx = fminf(bx2, gx2), rry = fminf(by2, gy2);
    float rw = fmaxf(rrx - rlx, 0.f), rh = fmaxf(rry - rly, 0.f);
    float rinter = rw * rh;
    float ra1 = (bx2 - bx1) * (by2 - by1);
    float ra2 = (gx2 - gx1) * (gy2 - gy1);
    float runi = ra1 + ra2 - rinter;
    float riou = rinter / (runi + EPS);
    ious[nb_off * M_ + m] = valid ? riou : 0.f;
  }
}

// ------------------------------------------------------------------
// K3: SimOTA column matching. One block per (b,m).
// Zero-inits its own matching column (replaces a hipMemsetAsync node —
// column-private, no cross-block hazard; loss_kernel runs next node).
__global__ __launch_bounds__(256) void match_kernel(
    const float* __restrict__ cost, const float* __restrict__ ious,
    float* __restrict__ matching) {
  int b = blockIdx.x / M_, m = blockIdx.x - b * M_;
  int tid = threadIdx.x;
  __shared__ float cc[N_], io[N_];
  __shared__ float swv[4];
  __shared__ int swi[4];
  __shared__ int s_dk;
  for (int n = tid; n < N_; n += 256) {
    cc[n] = cost[(size_t)(b * N_ + n) * M_ + m];
    io[n] = ious[(size_t)(b * N_ + n) * M_ + m];
    matching[(size_t)(b * N_ + n) * M_ + m] = 0.f;
  }
  __syncthreads();
  int lane = tid & 63, w = tid >> 6;
  float s = 0.f;  // meaningful on tid 0 only
  for (int k = 0; k < CAND_K; ++k) {
    float bv = -1e30f; int bi = 0x7fffffff;
    for (int n = tid; n < N_; n += 256) {
      float v = io[n];
      if (v > bv || (v == bv && n < bi)) { bv = v; bi = n; }
    }
    for (int off = 32; off; off >>= 1) {
      float ov = __shfl_down(bv, off, 64);
      int oi = __shfl_down(bi, off, 64);
      if (ov > bv || (ov == bv && oi < bi)) { bv = ov; bi = oi; }
    }
    if (lane == 0) { swv[w] = bv; swi[w] = bi; }
    __syncthreads();
    if (tid == 0) {
      float Bv = swv[0]; int Bi = swi[0];
      for (int ww = 1; ww < 4; ++ww)
        if (swv[ww] > Bv || (swv[ww] == Bv && swi[ww] < Bi)) { Bv = swv[ww]; Bi = swi[ww]; }
      s += Bv;          // descending order, matches top_k().sum()
      io[Bi] = -1e30f;
    }
    __syncthreads();
  }
  if (tid == 0) {
    int dk = (int)s;              // astype(int32) truncation
    if (dk < 1) dk = 1;           // clip(..., 1, None)
    s_dk = dk;
  }
  __syncthreads();
  int dk = s_dk;
  for (int k = 0; k < CAND_K; ++k) {
    float bv = 1e30f; int bi = 0x7fffffff;
    for (int n = tid; n < N_; n += 256) {
      float v = cc[n];
      if (v < bv || (v == bv && n < bi)) { bv = v; bi = n; }
    }
    for (int off = 32; off; off >>= 1) {
      float ov = __shfl_down(bv, off, 64);
      int oi = __shfl_down(bi, off, 64);
      if (ov < bv || (ov == bv && oi < bi)) { bv = ov; bi = oi; }
    }
    if (lane == 0) { swv[w] = bv; swi[w] = bi; }
    __syncthreads();
    if (tid == 0) {
      float Bv = swv[0]; int Bi = swi[0];
      for (int ww = 1; ww < 4; ++ww)
        if (swv[ww] < Bv || (swv[ww] == Bv && swi[ww] < Bi)) { Bv = swv[ww]; Bi = swi[ww]; }
      if (k < dk) matching[(size_t)(b * N_ + Bi) * M_ + m] = 1.f;
      cc[Bi] = 1e30f;
    }
    __syncthreads();
  }
}

// ------------------------------------------------------------------
// K4: per-prediction losses. One wave (64 lanes) per (b,n).
__global__ __launch_bounds__(256) void loss_kernel(
    const float* __restrict__ logits, const float* __restrict__ boxes,
    const float* __restrict__ masks, const int* __restrict__ gcls,
    const float* __restrict__ gboxes, const float* __restrict__ imgsz,
    const float* __restrict__ gm, const float* __restrict__ gsum,
    const float* __restrict__ matching, const float* __restrict__ cost,
    const float* __restrict__ validf, float* __restrict__ acc) {
  int gid = blockIdx.x * blockDim.x + threadIdx.x;
  int wid = gid >> 6;
  int lane = threadIdx.x & 63;
  if (wid >= B_ * N_) return;
  int b = wid / N_, n = wid - b * N_;
  size_t nb_off = (size_t)(b * N_ + n);

  int matched = 0, fg = 0;
  if (lane == 0) {
    const float* mrow = matching + nb_off * M_;
    const float* crow = cost + nb_off * M_;
    float msum = 0.f; int first = -1;
    for (int m = 0; m < M_; ++m) {
      float v = mrow[m];
      msum += v;
      if (first < 0 && v > 0.5f) first = m;
    }
    float fgs;
    if (msum > 1.f) {                 // multi: replace with one_hot(argmin cost)
      float bv = crow[0]; int bi = 0;
      for (int m = 1; m < M_; ++m) if (crow[m] < bv) { bv = crow[m]; bi = m; }
      matched = bi; fgs = 1.f;
    } else {
      matched = (first >= 0) ? first : 0;   // argmax of 0/1 row, first occurrence
      fgs = msum;
    }
    fg = (fgs > 0.f && validf[nb_off] > 0.5f) ? 1 : 0;
  }
  matched = __shfl(matched, 0, 64);
  fg = __shfl(fg, 0, 64);
  if (!fg) return;

  int tcls = gcls[b * M_ + matched];
  // focal loss over all C classes
  float fsum = 0.f;
  for (int c = lane; c < C_; c += 64) {
    float l = logits[nb_off * C_ + c];
    float p = 1.f / (1.f + expf(-l));
    float tgt = (c == tcls) ? 1.f : 0.f;
    float ce = fmaxf(l, 0.f) - l * tgt + log1pf(expf(-fabsf(l)));
    float pt = p * tgt + (1.f - p) * (1.f - tgt);
    float om = 1.f - pt;
    float wf = 0.25f * tgt + 0.75f * (1.f - tgt);
    fsum += ce * om * om * wf;
  }
  // dice loss vs matched gt mask
  float mi = 0.f, ps = 0.f;
  const float* pmrow = masks + (nb_off * C_ + tcls) * TT;
  const float* gmrow = gm + (size_t)(b * M_ + matched) * TT;
  for (int t = lane; t < TT; t += 64) {
    float pm = 1.f / (1.f + expf(-pmrow[t]));
    mi += pm * gmrow[t];
    ps += pm;
  }
  for (int off = 32; off; off >>= 1) {
    fsum += __shfl_down(fsum, off, 64);
    mi   += __shfl_down(mi, off, 64);
    ps   += __shfl_down(ps, off, 64);
  }
  if (lane == 0) {
    float bx1 = boxes[nb_off*4+0], by1 = boxes[nb_off*4+1];
    float bx2 = boxes[nb_off*4+2], by2 = boxes[nb_off*4+3];
    int gi = (b * M_ + matched) * 4;
    float gx1 = gboxes[gi+0], gy1 = gboxes[gi+1], gx2 = gboxes[gi+2], gy2 = gboxes[gi+3];
    float s0 = imgsz[b*4+0], s1 = imgsz[b*4+1], s2 = imgsz[b*4+2], s3 = imgsz[b*4+3];
    float nbx1 = bx1/s0, nby1 = by1/s1, nbx2 = bx2/s2, nby2 = by2/s3;
    float ngx1 = gx1/s0, ngy1 = gy1/s1, ngx2 = gx2/s2, ngy2 = gy2/s3;
    float l1 = fabsf(nbx1-ngx1) + fabsf(nby1-ngy1) + fabsf(nbx2-ngx2) + fabsf(nby2-ngy2);
    float ilx = fmaxf(nbx1, ngx1), ily = fmaxf(nby1, ngy1);
    float irx = fminf(nbx2, ngx2), iry = fminf(nby2, ngy2);
    float iw = fmaxf(irx - ilx, 0.f), ih = fmaxf(iry - ily, 0.f);
    float inter = iw * ih;
    float a1 = (nbx2 - nbx1) * (nby2 - nby1);
    float a2 = (ngx2 - ngx1) * (ngy2 - ngy1);
    float uni = a1 + a2 - inter;
    float iou = inter / (uni + EPS);
    float elx = fminf(nbx1, ngx1), ely = fminf(nby1, ngy1);
    float erx = fmaxf(nbx2, ngx2), ery = fmaxf(nby2, ngy2);
    float ew = fmaxf(erx - elx, 0.f), eh = fmaxf(ery - ely, 0.f);
    float enc = ew * eh;
    float giou = iou - (enc - uni) / (enc + EPS);
    float gterm = 1.f - giou;
    float mu = ps + gsum[b * M_ + matched] + EPS;
    float mterm = 1.f - 2.f * mi / mu;
    atomicAdd(&acc[0], fsum);
    atomicAdd(&acc[1], l1);
    atomicAdd(&acc[2], gterm);
    atomicAdd(&acc[3], mterm);
    atomicAdd(&acc[4], 1.f);
  }
}

// ------------------------------------------------------------------
__global__ void finalize_kernel(const float* __restrict__ acc, float* __restrict__ out) {
  if (threadIdx.x == 0 && blockIdx.x == 0) {
    float nf = acc[4];
    out[0] = 2.f * acc[0] / nf;   // CLS_W
    out[1] = 5.f * acc[1] / nf;   // L1_W
    out[2] = 2.f * acc[2] / nf;   // GIOU_W
    out[3] = 5.f * acc[3] / nf;   // MASK_W
  }
}

// ------------------------------------------------------------------
extern "C" void kernel_launch(void* const* d_in, const int* in_sizes, int n_in,
                              void* d_out, int out_size, void* d_ws, size_t ws_size,
                              hipStream_t stream) {
  const float* logits = (const float*)d_in[0];
  const float* boxes  = (const float*)d_in[1];
  const float* masks  = (const float*)d_in[2];
  const int*   gcls   = (const int*)d_in[3];
  const float* gboxes = (const float*)d_in[4];
  const float* gtm    = (const float*)d_in[5];
  const float* imgsz  = (const float*)d_in[6];

  float* ws       = (float*)d_ws;
  float* gm       = ws + OFF_GM;
  float* gsum     = ws + OFF_GSUM;
  float* cost     = ws + OFF_COST;
  float* ious     = ws + OFF_IOUS;
  float* matching = ws + OFF_MATCH;
  float* validf   = ws + OFF_VALID;
  float* acc      = ws + OFF_ACC;

  crop_kernel<<<B_ * M_, 256, 0, stream>>>(gtm, gboxes, gm, gsum, acc);
  cost_kernel<<<B_ * N_, 256, 0, stream>>>(logits, boxes, masks, gcls, gboxes,
                                           imgsz, gm, gsum, cost, ious, validf);
  match_kernel<<<B_ * M_, 256, 0, stream>>>(cost, ious, matching);
  loss_kernel<<<(B_ * N_ * 64 + 255) / 256, 256, 0, stream>>>(
      logits, boxes, masks, gcls, gboxes, imgsz, gm, gsum, matching, cost,
      validf, acc);
  finalize_kernel<<<1, 64, 0, stream>>>(acc, (float*)d_out);
}

// Round 3
// 680.144 us; speedup vs baseline: 1.0208x; 1.0073x over previous
//
#include <hip/hip_runtime.h>
#include <math.h>

// Problem constants (match reference)
#define B_ 4
#define N_ 500
#define C_ 80
#define T_ 28
#define TT 784       // T*T
#define M_ 16
#define H_ 800
#define W_ 800
#define CAND_K 10
#define EPS 1e-8f

// ---- workspace layout (in floats) ----
#define OFF_GM    0                          // [B][M][TT] binarized cropped gt masks
#define OFF_GSUM  (OFF_GM + B_*M_*TT)        // [B][M]
#define OFF_COST  (OFF_GSUM + B_*M_)         // [B][N][M]
#define OFF_IOUS  (OFF_COST + B_*N_*M_)      // [B][N][M]
#define OFF_MATCH (OFF_IOUS + B_*N_*M_)      // [B][N][M]
#define OFF_SSUM  (OFF_MATCH + B_*N_*M_)     // [B][N][M] sigmoid-sum (valid rows only)
#define OFF_INTER (OFF_SSUM + B_*N_*M_)      // [B][N][M] sigmoid·gm   (valid rows only)
#define OFF_VALID (OFF_INTER + B_*N_*M_)     // [B][N]
#define OFF_ACC   (OFF_VALID + B_*N_)        // [0..4] cls,l1,giou,mask,num_fg; [6] int counter

// ------------------------------------------------------------------
// K1: ROIAlign-style bilinear crop of gt mask to 28x28, binarize >=0.5.
// One block per (b,m). Block 0 zero-inits loss accumulators + counter.
// 4-way unrolled so up to 16 scattered loads are in flight per thread.
__global__ __launch_bounds__(256) void crop_kernel(
    const float* __restrict__ gtm, const float* __restrict__ gboxes,
    float* __restrict__ gm, float* __restrict__ gsum, float* __restrict__ acc) {
  if (blockIdx.x == 0 && threadIdx.x < 8) acc[threadIdx.x] = 0.f;
  int bm = blockIdx.x;
  const float* img = gtm + (size_t)bm * (H_ * W_);
  float x1 = gboxes[bm*4+0], y1 = gboxes[bm*4+1];
  float x2 = gboxes[bm*4+2], y2 = gboxes[bm*4+3];
  float part = 0.f;
#pragma unroll
  for (int r = 0; r < 4; ++r) {
    int t = threadIdx.x + r * 256;
    bool on = t < TT;
    int tc = on ? t : 0;
    int i = tc / T_, j = tc - i * T_;
    float y = y1 + (i + 0.5f) * (y2 - y1) / T_ - 0.5f;
    float x = x1 + (j + 0.5f) * (x2 - x1) / T_ - 0.5f;
    int y0 = (int)floorf(y), x0 = (int)floorf(x);
    float fy = y - (float)y0, fx = x - (float)x0;
    float v = 0.f;
#pragma unroll
    for (int dy = 0; dy < 2; ++dy)
#pragma unroll
      for (int dx = 0; dx < 2; ++dx) {
        int yy = y0 + dy, xx = x0 + dx;
        float w = (dy ? fy : 1.f - fy) * (dx ? fx : 1.f - fx);
        if (on && yy >= 0 && yy < H_ && xx >= 0 && xx < W_)
          v += w * img[yy * W_ + xx];
      }
    if (on) {
      float g = (v >= 0.5f) ? 1.f : 0.f;
      gm[(size_t)bm * TT + t] = g;
      part += g;
    }
  }
  __shared__ float sb[4];
  for (int off = 32; off; off >>= 1) part += __shfl_down(part, off, 64);
  int lane = threadIdx.x & 63, w = threadIdx.x >> 6;
  if (lane == 0) sb[w] = part;
  __syncthreads();
  if (threadIdx.x == 0) gsum[bm] = sb[0] + sb[1] + sb[2] + sb[3];
}

// ------------------------------------------------------------------
// K2: cost matrix + raw ious + valid + (ssum,inter) spill. One block per (b,n).
// valid is block-uniform: invalid blocks skip the 50 KB mask read entirely
// (output-invariant: dice of invalid rows only reorders invalid rows among
// themselves in the column top-k, and invalid rows never become fg).
// Wave w owns m = {w, w+4, w+8, w+12}; m- and t-loops fully unrolled so all
// float4 loads issue up front (memory-level parallelism).
__global__ __launch_bounds__(256) void cost_kernel(
    const float* __restrict__ logits, const float* __restrict__ boxes,
    const float* __restrict__ masks, const int* __restrict__ gcls,
    const float* __restrict__ gboxes, const float* __restrict__ imgsz,
    const float* __restrict__ gm, const float* __restrict__ gsum,
    float* __restrict__ cost, float* __restrict__ ious,
    float* __restrict__ validf, float* __restrict__ ssumb,
    float* __restrict__ interb) {
  int blk = blockIdx.x;
  int b = blk / N_, n = blk - b * N_;
  int tid = threadIdx.x;
  int lane = tid & 63, wave = tid >> 6;
  __shared__ float s_ssum[M_], s_inter[M_];
  const size_t nb_off = (size_t)(b * N_ + n);

  // ---- validity (redundantly per wave: lanes 0..15 test, wave ballot) ----
  float bx1 = boxes[nb_off*4+0], by1 = boxes[nb_off*4+1];
  float bx2 = boxes[nb_off*4+2], by2 = boxes[nb_off*4+3];
  float cx = (bx1 + bx2) * 0.5f, cy = (by1 + by2) * 0.5f;
  bool flag = false, in_box = false, in_ctr = false;
  float gx1 = 0, gy1 = 0, gx2 = 0, gy2 = 0;
  if (lane < M_) {
    int gi = (b * M_ + lane) * 4;
    gx1 = gboxes[gi+0]; gy1 = gboxes[gi+1]; gx2 = gboxes[gi+2]; gy2 = gboxes[gi+3];
    in_box = (cx > gx1) && (cx < gx2) && (cy > gy1) && (cy < gy2);
    float gcx = (gx1 + gx2) * 0.5f, gcy = (gy1 + gy2) * 0.5f;
    float gw = gx2 - gx1, gh = gy2 - gy1;
    in_ctr = (fabsf(cx - gcx) < 0.25f * gw) && (fabsf(cy - gcy) < 0.25f * gh);
    flag = in_box || in_ctr;
  }
  bool valid = (__ballot(flag) != 0ULL);   // wave-uniform, same in all 4 waves

  // ---- 16 cooperative reductions (valid blocks only) ----
  if (valid) {
    const float* mbase = masks + nb_off * C_ * TT;
    const float* gbase = gm + (size_t)b * M_ * TT;
#pragma unroll
    for (int mm = 0; mm < 4; ++mm) {
      int m = wave + mm * 4;
      int gc = gcls[b * M_ + m];
      const float4* mp = (const float4*)(mbase + (size_t)gc * TT);
      const float4* gp = (const float4*)(gbase + (size_t)m * TT);
      // 196 float4 chunks: lanes read t=lane, lane+64, lane+128, (+192 if lane<4)
      float4 a0 = mp[lane], a1 = mp[lane + 64], a2 = mp[lane + 128];
      float4 g0 = gp[lane], g1 = gp[lane + 64], g2 = gp[lane + 128];
      float4 a3 = make_float4(0,0,0,0), g3 = make_float4(0,0,0,0);
      if (lane < 4) { a3 = mp[192 + lane]; g3 = gp[192 + lane]; }
      float si = 0.f, sg = 0.f;
      {
        float p0 = 1.f/(1.f+expf(-a0.x)), p1 = 1.f/(1.f+expf(-a0.y));
        float p2 = 1.f/(1.f+expf(-a0.z)), p3 = 1.f/(1.f+expf(-a0.w));
        si += p0+p1+p2+p3; sg += p0*g0.x+p1*g0.y+p2*g0.z+p3*g0.w;
      }
      {
        float p0 = 1.f/(1.f+expf(-a1.x)), p1 = 1.f/(1.f+expf(-a1.y));
        float p2 = 1.f/(1.f+expf(-a1.z)), p3 = 1.f/(1.f+expf(-a1.w));
        si += p0+p1+p2+p3; sg += p0*g1.x+p1*g1.y+p2*g1.z+p3*g1.w;
      }
      {
        float p0 = 1.f/(1.f+expf(-a2.x)), p1 = 1.f/(1.f+expf(-a2.y));
        float p2 = 1.f/(1.f+expf(-a2.z)), p3 = 1.f/(1.f+expf(-a2.w));
        si += p0+p1+p2+p3; sg += p0*g2.x+p1*g2.y+p2*g2.z+p3*g2.w;
      }
      if (lane < 4) {
        float p0 = 1.f/(1.f+expf(-a3.x)), p1 = 1.f/(1.f+expf(-a3.y));
        float p2 = 1.f/(1.f+expf(-a3.z)), p3 = 1.f/(1.f+expf(-a3.w));
        si += p0+p1+p2+p3; sg += p0*g3.x+p1*g3.y+p2*g3.z+p3*g3.w;
      }
      for (int off = 32; off; off >>= 1) {
        si += __shfl_down(si, off, 64);
        sg += __shfl_down(sg, off, 64);
      }
      if (lane == 0) { s_ssum[m] = si; s_inter[m] = sg; }
    }
  }
  __syncthreads();   // the ONLY block barrier

  if (tid == 0) validf[nb_off] = valid ? 1.f : 0.f;

  // ---- per-(n,m) scalar epilogue on threads 0..15 (wave 0) ----
  if (tid < M_) {
    int m = tid;
    int gc = gcls[b * M_ + m];
    float lg = logits[nb_off * C_ + gc];
    float p = 1.f / (1.f + expf(-lg));
    float pos = -logf(p + EPS) * 0.25f * (1.f - p) * (1.f - p);
    float neg = -logf(1.f - p + EPS) * 0.75f * p * p;
    float ccost = 2.f * (pos - neg);
    float s0 = imgsz[b*4+0], s1 = imgsz[b*4+1], s2 = imgsz[b*4+2], s3 = imgsz[b*4+3];
    float nbx1 = bx1/s0, nby1 = by1/s1, nbx2 = bx2/s2, nby2 = by2/s3;
    float ngx1 = gx1/s0, ngy1 = gy1/s1, ngx2 = gx2/s2, ngy2 = gy2/s3;
    float l1 = 5.f * (fabsf(nbx1-ngx1) + fabsf(nby1-ngy1) +
                      fabsf(nbx2-ngx2) + fabsf(nby2-ngy2));
    float ilx = fmaxf(nbx1, ngx1), ily = fmaxf(nby1, ngy1);
    float irx = fminf(nbx2, ngx2), iry = fminf(nby2, ngy2);
    float iw = fmaxf(irx - ilx, 0.f), ih = fmaxf(iry - ily, 0.f);
    float inter = iw * ih;
    float a1 = (nbx2 - nbx1) * (nby2 - nby1);
    float a2 = (ngx2 - ngx1) * (ngy2 - ngy1);
    float uni = a1 + a2 - inter;
    float iou = inter / (uni + EPS);
    float elx = fminf(nbx1, ngx1), ely = fminf(nby1, ngy1);
    float erx = fmaxf(nbx2, ngx2), ery = fmaxf(nby2, ngy2);
    float ew = fmaxf(erx - elx, 0.f), eh = fmaxf(ery - ely, 0.f);
    float enc = ew * eh;
    float giou = iou - (enc - uni) / (enc + EPS);
    float gcost = 2.f * (1.f - giou);
    float mcost = valid
        ? 5.f * (1.f - 2.f * s_inter[m] / (s_ssum[m] + gsum[b*M_+m] + EPS))
        : 0.f;
    float c = ccost + l1 + gcost + mcost;
    if (!(in_box && in_ctr)) c += 1e5f;
    if (!valid) c += 1e9f;
    cost[nb_off * M_ + m] = c;
    if (valid) {           // spill for loss_kernel's dice reuse
      ssumb[nb_off * M_ + m] = s_ssum[m];
      interb[nb_off * M_ + m] = s_inter[m];
    }
    // raw-pixel iou for dynamic-k
    float rlx = fmaxf(bx1, gx1), rly = fmaxf(by1, gy1);
    float rrx = fminf(bx2, gx2), rry = fminf(by2, gy2);
    float rw = fmaxf(rrx - rlx, 0.f), rh = fmaxf(rry - rly, 0.f);
    float rinter = rw * rh;
    float ra1 = (bx2 - bx1) * (by2 - by1);
    float ra2 = (gx2 - gx1) * (gy2 - gy1);
    float runi = ra1 + ra2 - rinter;
    float riou = rinter / (runi + EPS);
    ious[nb_off * M_ + m] = valid ? riou : 0.f;
  }
}

// ------------------------------------------------------------------
// K3: SimOTA column matching. ONE WAVE per (b,m) column: all 500 entries in
// 8 regs/lane, pure shfl argmax/argmin, zero barriers/LDS. matching written
// exactly once at the end (selection tracked in registers).
__global__ __launch_bounds__(64) void match_kernel(
    const float* __restrict__ cost, const float* __restrict__ ious,
    float* __restrict__ matching) {
  int b = blockIdx.x / M_, m = blockIdx.x - b * M_;
  int lane = threadIdx.x;       // 0..63
  int base = b * N_;
  float io[8], cc[8], msel[8];
#pragma unroll
  for (int r = 0; r < 8; ++r) {
    int n = lane + 64 * r;
    msel[r] = 0.f;
    if (n < N_) {
      io[r] = ious[(size_t)(base + n) * M_ + m];
      cc[r] = cost[(size_t)(base + n) * M_ + m];
    } else { io[r] = -1e30f; cc[r] = 1e30f; }
  }
  // top-10 iou values, descending, sum -> dyn_k
  float s = 0.f;
  for (int k = 0; k < CAND_K; ++k) {
    float bv = -1e30f; int bi = 0x7fffffff;
#pragma unroll
    for (int r = 0; r < 8; ++r) {
      int n = lane + 64 * r;
      if (io[r] > bv) { bv = io[r]; bi = n; }   // ascending n: first==smallest
    }
    for (int off = 32; off; off >>= 1) {
      float ov = __shfl_down(bv, off, 64);
      int oi = __shfl_down(bi, off, 64);
      if (ov > bv || (ov == bv && oi < bi)) { bv = ov; bi = oi; }
    }
    bv = __shfl(bv, 0, 64); bi = __shfl(bi, 0, 64);
    s += bv;
    int rsel = bi >> 6;
#pragma unroll
    for (int r = 0; r < 8; ++r)
      if (r == rsel && (bi & 63) == lane) io[r] = -1e30f;
  }
  int dk = (int)s;              // astype(int32) truncation
  if (dk < 1) dk = 1;           // clip(..., 1, None)
  // top-10 lowest-cost indices, first dk get matching=1
  for (int k = 0; k < CAND_K; ++k) {
    float bv = 1e30f; int bi = 0x7fffffff;
#pragma unroll
    for (int r = 0; r < 8; ++r) {
      int n = lane + 64 * r;
      if (cc[r] < bv) { bv = cc[r]; bi = n; }
    }
    for (int off = 32; off; off >>= 1) {
      float ov = __shfl_down(bv, off, 64);
      int oi = __shfl_down(bi, off, 64);
      if (ov < bv || (ov == bv && oi < bi)) { bv = ov; bi = oi; }
    }
    bi = __shfl(bi, 0, 64);
    int rsel = bi >> 6;
#pragma unroll
    for (int r = 0; r < 8; ++r)
      if (r == rsel && (bi & 63) == lane) {
        cc[r] = 1e30f;
        if (k < dk) msel[r] = 1.f;
      }
  }
#pragma unroll
  for (int r = 0; r < 8; ++r) {
    int n = lane + 64 * r;
    if (n < N_) matching[(size_t)(base + n) * M_ + m] = msel[r];
  }
}

// ------------------------------------------------------------------
// K4: per-prediction losses + fused finalize. One wave per (b,n); dice terms
// are gathered from cost_kernel's (ssum,inter) spill — no mask re-read.
// Last block (atomic counter) computes the 4 outputs.
__global__ __launch_bounds__(256) void loss_kernel(
    const float* __restrict__ logits, const float* __restrict__ boxes,
    const int* __restrict__ gcls, const float* __restrict__ gboxes,
    const float* __restrict__ imgsz, const float* __restrict__ gsum,
    const float* __restrict__ matching, const float* __restrict__ cost,
    const float* __restrict__ validf, const float* __restrict__ ssumb,
    const float* __restrict__ interb, float* __restrict__ acc,
    float* __restrict__ out) {
  int wid = blockIdx.x * 4 + (threadIdx.x >> 6);   // 0..B*N-1 (grid=500 exact)
  int lane = threadIdx.x & 63;
  {
    int b = wid / N_, n = wid - b * N_;
    size_t nb_off = (size_t)(b * N_ + n);
    int matched = 0, fg = 0;
    if (lane == 0) {
      const float* mrow = matching + nb_off * M_;
      const float* crow = cost + nb_off * M_;
      float msum = 0.f; int first = -1;
      for (int m = 0; m < M_; ++m) {
        float v = mrow[m];
        msum += v;
        if (first < 0 && v > 0.5f) first = m;
      }
      float fgs;
      if (msum > 1.f) {               // multi: one_hot(argmin cost)
        float bv = crow[0]; int bi = 0;
        for (int m = 1; m < M_; ++m) if (crow[m] < bv) { bv = crow[m]; bi = m; }
        matched = bi; fgs = 1.f;
      } else {
        matched = (first >= 0) ? first : 0;
        fgs = msum;
      }
      fg = (fgs > 0.f && validf[nb_off] > 0.5f) ? 1 : 0;
    }
    matched = __shfl(matched, 0, 64);
    fg = __shfl(fg, 0, 64);
    if (fg) {
      int tcls = gcls[b * M_ + matched];
      float fsum = 0.f;
#pragma unroll
      for (int rr = 0; rr < 2; ++rr) {
        int c = lane + 64 * rr;
        if (c < C_) {
          float l = logits[nb_off * C_ + c];
          float p = 1.f / (1.f + expf(-l));
          float tgt = (c == tcls) ? 1.f : 0.f;
          float ce = fmaxf(l, 0.f) - l * tgt + log1pf(expf(-fabsf(l)));
          float pt = p * tgt + (1.f - p) * (1.f - tgt);
          float om = 1.f - pt;
          float wf = 0.25f * tgt + 0.75f * (1.f - tgt);
          fsum += ce * om * om * wf;
        }
      }
      for (int off = 32; off; off >>= 1) fsum += __shfl_down(fsum, off, 64);
      if (lane == 0) {
        float bx1 = boxes[nb_off*4+0], by1 = boxes[nb_off*4+1];
        float bx2 = boxes[nb_off*4+2], by2 = boxes[nb_off*4+3];
        int gi = (b * M_ + matched) * 4;
        float gx1 = gboxes[gi+0], gy1 = gboxes[gi+1];
        float gx2 = gboxes[gi+2], gy2 = gboxes[gi+3];
        float s0 = imgsz[b*4+0], s1 = imgsz[b*4+1], s2 = imgsz[b*4+2], s3 = imgsz[b*4+3];
        float nbx1 = bx1/s0, nby1 = by1/s1, nbx2 = bx2/s2, nby2 = by2/s3;
        float ngx1 = gx1/s0, ngy1 = gy1/s1, ngx2 = gx2/s2, ngy2 = gy2/s3;
        float l1 = fabsf(nbx1-ngx1) + fabsf(nby1-ngy1) + fabsf(nbx2-ngx2) + fabsf(nby2-ngy2);
        float ilx = fmaxf(nbx1, ngx1), ily = fmaxf(nby1, ngy1);
        float irx = fminf(nbx2, ngx2), iry = fminf(nby2, ngy2);
        float iw = fmaxf(irx - ilx, 0.f), ih = fmaxf(iry - ily, 0.f);
        float inter = iw * ih;
        float a1 = (nbx2 - nbx1) * (nby2 - nby1);
        float a2 = (ngx2 - ngx1) * (ngy2 - ngy1);
        float uni = a1 + a2 - inter;
        float iou = inter / (uni + EPS);
        float elx = fminf(nbx1, ngx1), ely = fminf(nby1, ngy1);
        float erx = fmaxf(nbx2, ngx2), ery = fmaxf(nby2, ngy2);
        float ew = fmaxf(erx - elx, 0.f), eh = fmaxf(ery - ely, 0.f);
        float enc = ew * eh;
        float giou = iou - (enc - uni) / (enc + EPS);
        float mi = interb[nb_off * M_ + matched];
        float ps = ssumb[nb_off * M_ + matched];
        float mu = ps + gsum[b * M_ + matched] + EPS;
        atomicAdd(&acc[0], fsum);
        atomicAdd(&acc[1], l1);
        atomicAdd(&acc[2], 1.f - giou);
        atomicAdd(&acc[3], 1.f - 2.f * mi / mu);
        atomicAdd(&acc[4], 1.f);
      }
    }
  }
  __syncthreads();
  if (threadIdx.x == 0) {
    __threadfence();
    int old = atomicAdd((int*)&acc[6], 1);
    if (old == (int)gridDim.x - 1) {     // last block: finalize
      float a0 = atomicAdd(&acc[0], 0.f);
      float a1 = atomicAdd(&acc[1], 0.f);
      float a2 = atomicAdd(&acc[2], 0.f);
      float a3 = atomicAdd(&acc[3], 0.f);
      float nf = atomicAdd(&acc[4], 0.f);
      out[0] = 2.f * a0 / nf;   // CLS_W
      out[1] = 5.f * a1 / nf;   // L1_W
      out[2] = 2.f * a2 / nf;   // GIOU_W
      out[3] = 5.f * a3 / nf;   // MASK_W
    }
  }
}

// ------------------------------------------------------------------
extern "C" void kernel_launch(void* const* d_in, const int* in_sizes, int n_in,
                              void* d_out, int out_size, void* d_ws, size_t ws_size,
                              hipStream_t stream) {
  const float* logits = (const float*)d_in[0];
  const float* boxes  = (const float*)d_in[1];
  const float* masks  = (const float*)d_in[2];
  const int*   gcls   = (const int*)d_in[3];
  const float* gboxes = (const float*)d_in[4];
  const float* gtm    = (const float*)d_in[5];
  const float* imgsz  = (const float*)d_in[6];

  float* ws       = (float*)d_ws;
  float* gm       = ws + OFF_GM;
  float* gsum     = ws + OFF_GSUM;
  float* cost     = ws + OFF_COST;
  float* ious     = ws + OFF_IOUS;
  float* matching = ws + OFF_MATCH;
  float* ssumb    = ws + OFF_SSUM;
  float* interb   = ws + OFF_INTER;
  float* validf   = ws + OFF_VALID;
  float* acc      = ws + OFF_ACC;

  crop_kernel<<<B_ * M_, 256, 0, stream>>>(gtm, gboxes, gm, gsum, acc);
  cost_kernel<<<B_ * N_, 256, 0, stream>>>(logits, boxes, masks, gcls, gboxes,
                                           imgsz, gm, gsum, cost, ious, validf,
                                           ssumb, interb);
  match_kernel<<<B_ * M_, 64, 0, stream>>>(cost, ious, matching);
  loss_kernel<<<B_ * N_ / 4, 256, 0, stream>>>(
      logits, boxes, gcls, gboxes, imgsz, gsum, matching, cost, validf,
      ssumb, interb, acc, (float*)d_out);
}